// Round 6
// baseline (1897.877 us; speedup 1.0000x reference)
//
#include <hip/hip_runtime.h>
#include <math.h>

#define Bsz 8192
#define Hd  512
#define Vd  512
#define Ld  16
#define G4  2048   // 4*Hd
#define BM  32     // batch rows per block; 256 blocks = 1/CU

using int4v = __attribute__((ext_vector_type(4))) int;

__device__ __forceinline__ float sigm_f(float x){
  return __builtin_amdgcn_rcpf(1.0f + __expf(-x));
}
__device__ __forceinline__ float tanh_f(float x){
  return 1.0f - 2.0f * __builtin_amdgcn_rcpf(1.0f + __expf(2.0f * x));
}

// int16 -> signed i8 pair: q = 256*a + b, a,b in [-128,127]
__device__ __forceinline__ void i16split(float x, float S, signed char& a, signed char& b){
  int q = (int)rintf(x * S);
  q = min(max(q, -32640), 32639);
  const int ah = (q + 128) >> 8;
  a = (signed char)ah;
  b = (signed char)(q - (ah << 8));
}

__device__ __forceinline__ void gl_lds16(const void* g, void* l){
  __builtin_amdgcn_global_load_lds((const __attribute__((address_space(1))) void*)g,
                                   (__attribute__((address_space(3))) void*)l, 16, 0, 0);
}

// reconstruction: value = (65536*acc1 + 256*acc2) / (Sw * Sh)
#define C1I (65536.0f / (524288.0f * 32767.0f))   // h plane scale 32767
#define C2I (  256.0f / (524288.0f * 32767.0f))
#define C1E (65536.0f / (524288.0f * 4096.0f))    // enc plane scale 4096 (step 0 gates)
#define C2E (  256.0f / (524288.0f * 4096.0f))

// ---------------------------------------------------------------------------
// Prologue kernels
// ---------------------------------------------------------------------------
// WihT' : [512 vocab][2048 gate-interleaved j*4+g] = Wih[g*512+j][v]
__global__ __launch_bounds__(256) void k_prep_wih(const float* __restrict__ in,
                                                  float* __restrict__ out){
  __shared__ float tile[32][33];
  const int tx = threadIdx.x, ty = threadIdx.y;
  const int v0 = blockIdx.x * 32, n0 = blockIdx.y * 32;   // n-tile within one gate block
#pragma unroll
  for(int i=0;i<4;i++)
    tile[ty+i*8][tx] = in[(size_t)(n0+ty+i*8)*Vd + v0+tx];
  __syncthreads();
  const int g = n0 >> 9, jb = n0 & 511;
#pragma unroll
  for(int i=0;i<4;i++)
    out[(size_t)(v0+ty+i*8)*G4 + (jb+tx)*4 + g] = tile[tx][ty+i*8];
}

// cT : [512][8192] = enc_c^T
__global__ __launch_bounds__(256) void k_tr_c(const float* __restrict__ in,
                                              float* __restrict__ out){
  __shared__ float tile[32][33];
  const int tx = threadIdx.x, ty = threadIdx.y;
  const int j0 = blockIdx.x * 32, b0 = blockIdx.y * 32;
#pragma unroll
  for(int i=0;i<4;i++)
    tile[ty+i*8][tx] = in[(size_t)(b0+ty+i*8)*Hd + j0+tx];
  __syncthreads();
#pragma unroll
  for(int i=0;i<4;i++)
    out[(size_t)(j0+ty+i*8)*Bsz + b0+tx] = tile[tx][ty+i*8];
}

// Whh split with gate-interleave row remap: out_row = (in_row&511)*4 + (in_row>>9)
__global__ __launch_bounds__(256) void k_split_whh(const float* __restrict__ src,
                                                   signed char* __restrict__ pa,
                                                   signed char* __restrict__ pb){
  const int i = blockIdx.x*256 + threadIdx.x;
  if(i < G4*Hd){
    const int in_row = i >> 9, k = i & 511;
    const int o_row = (in_row & 511)*4 + (in_row >> 9);
    signed char a, b;
    i16split(src[i], 524288.0f, a, b);
    pa[(size_t)o_row*Hd + k] = a;
    pb[(size_t)o_row*Hd + k] = b;
  }
}

__global__ __launch_bounds__(256) void k_split_i8(const float* __restrict__ src,
                                                  signed char* __restrict__ pa,
                                                  signed char* __restrict__ pb,
                                                  float S, int n){
  const int i = blockIdx.x*256 + threadIdx.x;
  if(i < n){
    signed char a, b;
    i16split(src[i], S, a, b);
    pa[i] = a; pb[i] = b;
  }
}

// bsum'[j*4+g] = bih[g*512+j] + bhh[g*512+j]
__global__ __launch_bounds__(256) void k_prep_bias(const float* __restrict__ bih,
                                                   const float* __restrict__ bhh,
                                                   float* __restrict__ out){
  const int i = blockIdx.x*256 + threadIdx.x;
  if(i < G4)
    out[(i & 511)*4 + (i >> 9)] = bih[i] + bhh[i];
}

// ---------------------------------------------------------------------------
// Fused per-step kernel: gates GEMM + activations + logits GEMM + softmax
// stats + argmax + lp/mask update + msg one-hot.  One dispatch per step.
// Block: 32 batch rows x ALL 512 j.  512 threads (8 waves).  1 block/CU.
// ---------------------------------------------------------------------------
template<bool FIRST>
__global__ __launch_bounds__(512, 2) void k_step(
    const signed char* __restrict__ hinA, const signed char* __restrict__ hinB,
    signed char* __restrict__ hA, signed char* __restrict__ hB,
    float* __restrict__ cT,
    const signed char* __restrict__ WgA, const signed char* __restrict__ WgB,
    const signed char* __restrict__ WoA, const signed char* __restrict__ WoB,
    const float* __restrict__ WihTi, const float* __restrict__ bsum,
    const float* __restrict__ bout,
    int* __restrict__ gIdx, float* __restrict__ lpbuf, float* __restrict__ mbuf,
    float* __restrict__ out_msg, float* __restrict__ out_masks,
    float* __restrict__ out_lp, int t)
{
  __shared__ signed char hin[2][16384];    // [plane][kc*2+n slab][16r][64]
  __shared__ signed char hout[2][16384];
  __shared__ signed char wbuf[2][2][16384];// [dbuf][plane][16 slabs]
  __shared__ float sM[8][32], sS[8][32];
  __shared__ int   sI[8][32], gIsh[32], gFin[32];

  const int tid = threadIdx.x;
  const int wave = tid >> 6, lane = tid & 63;
  const int mb = blockIdx.x * BM;
  const int fr = lane & 15, q = lane >> 4;
  const int lr = lane >> 2, jj = lane & 3;

  // stage 32KB of h planes (16 slabs/plane); wave-uniform LDS bases
  auto stage_hin = [&](){
#pragma unroll
    for(int p=0;p<4;p++){
      const int s = wave*4 + p;          // 0..31
      const int plane = s >> 4, sl = s & 15;
      const int row = mb + (sl & 1)*16 + lr;
      const int k = (sl >> 1)*64 + (jj ^ ((lr >> 1) & 3))*16;
      const signed char* src = plane ? hinB : hinA;
      gl_lds16(src + (size_t)row*Hd + k, &hin[plane][sl*1024]);
    }
  };
  // stage one [256 rows x 64k] x2-plane weight chunk into wbuf[buf]
  auto stage_w = [&](const signed char* A, const signed char* B,
                     int rowbase, int kc, int buf){
#pragma unroll
    for(int p=0;p<4;p++){
      const int s = wave*4 + p;          // 0..31
      const int plane = s >> 4, srow = s & 15;
      const int row = rowbase + srow*16 + lr;
      const int k = kc*64 + (jj ^ ((lr >> 1) & 3))*16;
      const signed char* src = plane ? B : A;
      gl_lds16(src + (size_t)row*Hd + k, &wbuf[buf][plane][srow*1024]);
    }
  };
  // linear stage index: 0..63 gates chunks, 64..79 logits chunks
  auto stage_lin = [&](int s){
    if(s < 64) stage_w(WgA, WgB, (s >> 3)*256, s & 7, s & 1);
    else       stage_w(WoA, WoB, ((s-64) >> 3)*256, s & 7, s & 1);
  };

  stage_hin();
  stage_lin(0);
  if(!FIRST){ if(tid < 32) gIsh[tid] = gIdx[mb + tid]; }

  const float c1 = FIRST ? C1E : C1I;
  const float c2 = FIRST ? C2E : C2I;

  // per-lane online-softmax state (logits phase), per n-tile
  float vm[2] = {-1e30f, -1e30f}, vs[2] = {0.0f, 0.0f};
  int   vi[2] = {0, 0};

  int4v acc1[2][2], acc2[2][2];
#pragma unroll
  for(int mt=0;mt<2;mt++)
#pragma unroll
    for(int n=0;n<2;n++){
      acc1[mt][n] = (int4v){0,0,0,0};
      acc2[mt][n] = (int4v){0,0,0,0};
    }

  for(int s=0; s<80; s++){
    __syncthreads();                      // drains vmcnt+lgkm: stage(s) & epilogue LDS done
    if(s+1 < 80) stage_lin(s+1);

    if(s == 64){
      // hout complete -> copy to global h planes (for next step's kernel)
#pragma unroll
      for(int p=0;p<4;p++){
        const int l = p*512 + tid;        // 0..2047 16B-chunks
        const int plane = l >> 10, li = l & 1023;
        const int sl = li >> 6, rr = (li >> 2) & 15, jq = li & 3;
        int4v v = *(const int4v*)&hout[plane][li*16];
        const int row = mb + (sl & 1)*16 + rr;
        const int k = (sl >> 1)*64 + (jq ^ ((rr >> 1) & 3))*16;
        signed char* dst = plane ? hB : hA;
        *(int4v*)&dst[(size_t)row*Hd + k] = v;
      }
    }

    const int kc = s & 7;
    const signed char* Wa = wbuf[s&1][0];
    const signed char* Wb = wbuf[s&1][1];
    const signed char* Ha = (s < 64) ? hin[0] : hout[0];
    const signed char* Hb = (s < 64) ? hin[1] : hout[1];

    int4v wAv[2], wBv[2], hf[2], lf[2];
#pragma unroll
    for(int mt=0;mt<2;mt++){
      const int off = (wave*2 + mt)*1024 + fr*64 + ((q ^ ((fr >> 1) & 3)) << 4);
      wAv[mt] = *(const int4v*)&Wa[off];
      wBv[mt] = *(const int4v*)&Wb[off];
    }
#pragma unroll
    for(int n=0;n<2;n++){
      const int off = (kc*2 + n)*1024 + fr*64 + ((q ^ ((fr >> 1) & 3)) << 4);
      hf[n] = *(const int4v*)&Ha[off];
      lf[n] = *(const int4v*)&Hb[off];
    }
#pragma unroll
    for(int mt=0;mt<2;mt++)
#pragma unroll
      for(int n=0;n<2;n++){
        acc1[mt][n] = __builtin_amdgcn_mfma_i32_16x16x64_i8(wAv[mt], hf[n], acc1[mt][n],0,0,0);
        acc2[mt][n] = __builtin_amdgcn_mfma_i32_16x16x64_i8(wAv[mt], lf[n], acc2[mt][n],0,0,0);
        acc2[mt][n] = __builtin_amdgcn_mfma_i32_16x16x64_i8(wBv[mt], hf[n], acc2[mt][n],0,0,0);
      }

    if(kc == 7){
      if(s < 64){
        // ---- gates epilogue: chunk nc covers j in [nc*64, nc*64+64)
        const int nc = s >> 3;
#pragma unroll
        for(int mt=0;mt<2;mt++){
          const int j = nc*64 + (wave*2 + mt)*4 + q;   // this lane's j
          const float4 bs = *(const float4*)&bsum[j*4];
#pragma unroll
          for(int n=0;n<2;n++){
            const int rl = n*16 + fr;
            const int row = mb + rl;
            float base[4] = {bs.x, bs.y, bs.z, bs.w};
            if(!FIRST){
              const float4 wx = *(const float4*)&WihTi[(size_t)gIsh[rl]*G4 + j*4];
              base[0]+=wx.x; base[1]+=wx.y; base[2]+=wx.z; base[3]+=wx.w;
            }
            float g4[4];
#pragma unroll
            for(int r=0;r<4;r++)
              g4[r] = fmaf(c1, (float)acc1[mt][n][r],
                      fmaf(c2, (float)acc2[mt][n][r], base[r]));
            const float I = sigm_f(g4[0]);
            const float F = sigm_f(g4[1]);
            const float G = tanh_f(g4[2]);
            const float O = sigm_f(g4[3]);
            const size_t cidx = (size_t)j*Bsz + row;
            const float cn = F*cT[cidx] + I*G;
            cT[cidx] = cn;
            const float hn = O*tanh_f(cn);
            signed char a, b;
            i16split(hn, 32767.0f, a, b);
            const int rr = rl & 15;
            const int addr = ((j >> 6)*2 + (rl >> 4))*1024 + rr*64
                           + ((((j >> 4) & 3) ^ ((rr >> 1) & 3)) << 4) + (j & 15);
            hout[0][addr] = a;
            hout[1][addr] = b;
            acc1[mt][n] = (int4v){0,0,0,0};
            acc2[mt][n] = (int4v){0,0,0,0};
          }
        }
      } else {
        // ---- logits epilogue: chunk vc covers vocab [vc*256, +256)
        const int vc = (s - 64) >> 3;
#pragma unroll
        for(int mt=0;mt<2;mt++){
          const int vb4 = vc*256 + (wave*2 + mt)*16 + q*4;
          const float4 bo = *(const float4*)&bout[vb4];
          const float bo4[4] = {bo.x, bo.y, bo.z, bo.w};
#pragma unroll
          for(int n=0;n<2;n++){
#pragma unroll
            for(int r=0;r<4;r++){
              const float lg = fmaf(C1I, (float)acc1[mt][n][r],
                               fmaf(C2I, (float)acc2[mt][n][r], bo4[r]));
              if(lg > vm[n]){
                vs[n] = vs[n]*__expf(vm[n] - lg) + 1.0f;
                vm[n] = lg; vi[n] = vb4 + r;
              } else {
                vs[n] += __expf(lg - vm[n]);
              }
            }
            acc1[mt][n] = (int4v){0,0,0,0};
            acc2[mt][n] = (int4v){0,0,0,0};
          }
        }
      }
    }
  }

  // ---- cross-lane merge (q groups share a row): xor 16, 32
#pragma unroll
  for(int n=0;n<2;n++){
#pragma unroll
    for(int off=16; off<64; off<<=1){
      const float vmo = __shfl_xor(vm[n], off);
      const float vso = __shfl_xor(vs[n], off);
      const int   vio = __shfl_xor(vi[n], off);
      if(vmo > vm[n]){ vs[n] = vs[n]*__expf(vm[n]-vmo) + vso; vm[n]=vmo; vi[n]=vio; }
      else if(vmo == vm[n]){ vs[n] += vso; vi[n] = min(vi[n], vio); }
      else vs[n] += vso*__expf(vmo - vm[n]);
    }
  }
  if(lane < 16){
#pragma unroll
    for(int n=0;n<2;n++){
      sM[wave][n*16+lane] = vm[n];
      sS[wave][n*16+lane] = vs[n];
      sI[wave][n*16+lane] = vi[n];
    }
  }
  __syncthreads();

  if(tid < 32){
    float M = sM[0][tid], S = sS[0][tid];
    int   I = sI[0][tid];
#pragma unroll
    for(int w=1;w<8;w++){
      const float Mo = sM[w][tid], So = sS[w][tid];
      const int   Io = sI[w][tid];
      if(Mo > M){ S = S*__expf(M-Mo) + So; M = Mo; I = Io; }
      else if(Mo == M){ S += So; I = min(I, Io); }
      else S += So*__expf(Mo - M);
    }
    const float logp = -__logf(S);
    const int row = mb + tid;
    const float mo = FIRST ? 1.0f : mbuf[row];
    const float lp = (FIRST ? 0.0f : lpbuf[row]) + logp*mo;
    out_masks[(size_t)t*Bsz + row] = mo;
    lpbuf[row] = lp;
    out_lp[row] = lp;
    mbuf[row] = mo * ((I == Vd-1) ? 0.0f : 1.0f);
    gIdx[row] = I;
    gFin[tid] = I;
  }
  __syncthreads();

  // ---- msg one-hot for THIS step: 32 rows x 512 cols
  {
    const int rowl = tid >> 4, c0 = (tid & 15)*32;
    const int gi = gFin[rowl];
    float* mrow = out_msg + ((size_t)t*Bsz + mb + rowl)*Vd;
#pragma unroll
    for(int i=0;i<8;i++){
      const int c = c0 + i*4;
      float4 v;
      v.x = (c   == gi) ? 1.0f : 0.0f;
      v.y = (c+1 == gi) ? 1.0f : 0.0f;
      v.z = (c+2 == gi) ? 1.0f : 0.0f;
      v.w = (c+3 == gi) ? 1.0f : 0.0f;
      *(float4*)&mrow[c] = v;
    }
  }
}

// ---------------------------------------------------------------------------
extern "C" void kernel_launch(void* const* d_in, const int* in_sizes, int n_in,
                              void* d_out, int out_size, void* d_ws, size_t ws_size,
                              hipStream_t stream) {
  const float* enc_h = (const float*)d_in[0];
  const float* enc_c = (const float*)d_in[1];
  const float* Wih   = (const float*)d_in[2];
  const float* Whh   = (const float*)d_in[3];
  const float* bih   = (const float*)d_in[4];
  const float* bhh   = (const float*)d_in[5];
  const float* Wout  = (const float*)d_in[6];
  const float* bout  = (const float*)d_in[7];

  float* out_msg   = (float*)d_out;                       // [16][8192][512]
  float* out_masks = out_msg + (size_t)Ld * Bsz * Vd;     // [16][1][8192]
  float* out_lp    = out_masks + (size_t)Ld * Bsz;        // [8192]

  char* ws = (char*)d_ws;
  float* WihTi = (float*)ws;            ws += (size_t)Vd * G4 * 4;   // 4 MB
  signed char* WgA = (signed char*)ws;  ws += (size_t)G4 * Hd;       // 1 MB
  signed char* WgB = (signed char*)ws;  ws += (size_t)G4 * Hd;
  signed char* WoA = (signed char*)ws;  ws += (size_t)Vd * Hd;       // 256 KB
  signed char* WoB = (signed char*)ws;  ws += (size_t)Vd * Hd;
  signed char* encA = (signed char*)ws; ws += (size_t)Bsz * Hd;      // 4 MB
  signed char* encB = (signed char*)ws; ws += (size_t)Bsz * Hd;
  signed char* hA  = (signed char*)ws;  ws += (size_t)Bsz * Hd;      // 4 MB (in-place per step)
  signed char* hB  = (signed char*)ws;  ws += (size_t)Bsz * Hd;
  float* cT    = (float*)ws;            ws += (size_t)Hd * Bsz * 4;  // 16 MB transposed c
  float* bsum  = (float*)ws;            ws += (size_t)G4 * 4;        // 8 KB
  int*   gIdx  = (int*)ws;              ws += (size_t)Bsz * 4;
  float* lpbuf = (float*)ws;            ws += (size_t)Bsz * 4;
  float* mbuf  = (float*)ws;            ws += (size_t)Bsz * 4;

  k_prep_wih<<<dim3(Vd/32, G4/32), dim3(32,8), 0, stream>>>(Wih, WihTi);
  k_tr_c<<<dim3(Hd/32, Bsz/32), dim3(32,8), 0, stream>>>(enc_c, cT);
  k_split_whh<<<(G4*Hd+255)/256, 256, 0, stream>>>(Whh, WgA, WgB);
  k_split_i8<<<(Vd*Hd+255)/256, 256, 0, stream>>>(Wout, WoA, WoB, 524288.0f, Vd*Hd);
  k_split_i8<<<(Bsz*Hd+255)/256, 256, 0, stream>>>(enc_h, encA, encB, 4096.0f, Bsz*Hd);
  k_prep_bias<<<(G4+255)/256, 256, 0, stream>>>(bih, bhh, bsum);

  for(int t=0; t<Ld; t++){
    if(t == 0){
      k_step<true><<<dim3(Bsz/BM), dim3(512), 0, stream>>>(
          encA, encB, hA, hB, cT, WgA, WgB, WoA, WoB, WihTi, bsum, bout,
          gIdx, lpbuf, mbuf, out_msg, out_masks, out_lp, 0);
    } else {
      k_step<false><<<dim3(Bsz/BM), dim3(512), 0, stream>>>(
          hA, hB, hA, hB, cT, WgA, WgB, WoA, WoB, WihTi, bsum, bout,
          gIdx, lpbuf, mbuf, out_msg, out_masks, out_lp, t);
    }
  }
}

// Round 7
// 1568.423 us; speedup vs baseline: 1.2101x; 1.2101x over previous
//
#include <hip/hip_runtime.h>
#include <math.h>

#define Bsz 8192
#define Hd  512
#define Vd  512
#define Ld  16
#define G4  2048   // 4*Hd
#define NSLAB 16   // 32-col vocab slabs

using int4v  = __attribute__((ext_vector_type(4))) int;

__device__ __forceinline__ float sigm_f(float x){
  return __builtin_amdgcn_rcpf(1.0f + __expf(-x));
}
__device__ __forceinline__ float tanh_f(float x){
  return 1.0f - 2.0f * __builtin_amdgcn_rcpf(1.0f + __expf(2.0f * x));
}

// int16 -> signed i8 pair: q = 256*a + b, a,b in [-128,127]
__device__ __forceinline__ void i16split(float x, float S, signed char& a, signed char& b){
  int q = (int)rintf(x * S);
  q = min(max(q, -32640), 32639);
  const int ah = (q + 128) >> 8;
  a = (signed char)ah;
  b = (signed char)(q - (ah << 8));
}

__device__ __forceinline__ void gl_lds16(const void* g, void* l){
  __builtin_amdgcn_global_load_lds((const __attribute__((address_space(1))) void*)g,
                                   (__attribute__((address_space(3))) void*)l, 16, 0, 0);
}

// reconstruction: value = (65536*acc1 + 256*acc2) / (Sw * Sh)
#define C1I (65536.0f / (524288.0f * 32767.0f))   // steps >=1 (Sh=32767)
#define C2I (  256.0f / (524288.0f * 32767.0f))
#define C1E (65536.0f / (524288.0f * 4096.0f))    // step 0 (Sh=4096)
#define C2E (  256.0f / (524288.0f * 4096.0f))

// ---------------------------------------------------------------------------
// XCD-aware tile remap (free; kept from R3).
// ---------------------------------------------------------------------------
__device__ __forceinline__ int xcd_tau(int nwg_div8){
  const int lin  = blockIdx.y * gridDim.x + blockIdx.x;
  const int xcd  = lin & 7;
  const int slot = lin >> 3;
  return xcd * nwg_div8 + slot;
}

// ---------------------------------------------------------------------------
// Fused prologue: Wih transpose + 3 i8 splits in ONE dispatch (was 4).
// ---------------------------------------------------------------------------
__global__ __launch_bounds__(256) void k_prep(
    const float* __restrict__ Wih, const float* __restrict__ Whh,
    const float* __restrict__ Wout, const float* __restrict__ enc_h,
    float* __restrict__ WihT,
    signed char* __restrict__ WhhA, signed char* __restrict__ WhhB,
    signed char* __restrict__ WoA, signed char* __restrict__ WoB,
    signed char* __restrict__ encA, signed char* __restrict__ encB)
{
  __shared__ float tile[32][33];
  const int tid = threadIdx.x;
  const int tx = tid & 31, ty = tid >> 5;

  // A: transpose Wih (2048x512 -> 512x2048), 1024 tiles of 32x32
  for(int w = blockIdx.x; w < 1024; w += gridDim.x){
    const int v0 = (w & 15) * 32, n0 = (w >> 4) * 32;
#pragma unroll
    for(int i=0;i<4;i++)
      tile[ty+i*8][tx] = Wih[(size_t)(n0+ty+i*8)*Vd + v0+tx];
    __syncthreads();
#pragma unroll
    for(int i=0;i<4;i++)
      WihT[(size_t)(v0+ty+i*8)*G4 + n0+tx] = tile[tx][ty+i*8];
    __syncthreads();
  }
  // B: split Whh
  for(size_t i = (size_t)blockIdx.x*256 + tid; i < (size_t)G4*Hd; i += (size_t)gridDim.x*256){
    signed char a, b; i16split(Whh[i], 524288.0f, a, b); WhhA[i]=a; WhhB[i]=b;
  }
  // C: split Wout
  for(size_t i = (size_t)blockIdx.x*256 + tid; i < (size_t)Vd*Hd; i += (size_t)gridDim.x*256){
    signed char a, b; i16split(Wout[i], 524288.0f, a, b); WoA[i]=a; WoB[i]=b;
  }
  // D: split enc_h
  for(size_t i = (size_t)blockIdx.x*256 + tid; i < (size_t)Bsz*Hd; i += (size_t)gridDim.x*256){
    signed char a, b; i16split(enc_h[i], 4096.0f, a, b); encA[i]=a; encB[i]=b;
  }
}

// ---------------------------------------------------------------------------
// Kernel A0 (step 0): i8 LSTM step from quantized enc_h (Sh=4096).
// R3 body + early c-tile register prefetch (epilogue latency hidden).
// ---------------------------------------------------------------------------
__global__ __launch_bounds__(256, 2) void k_lstm_i8_first(
    const signed char* __restrict__ hA, const signed char* __restrict__ hB,
    const float* __restrict__ cin,
    signed char* __restrict__ hoA, signed char* __restrict__ hoB,
    float* __restrict__ cout,
    const signed char* __restrict__ WA, const signed char* __restrict__ WB,
    const float* __restrict__ bih, const float* __restrict__ bhh)
{
  __shared__ unsigned char lds[2][32768];
  const int tid = threadIdx.x;
  const int wave = tid >> 6, lane = tid & 63;
  const int tau = xcd_tau(128);
  const int mb = (tau >> 4) * 128;
  const int jb = (tau & 15) * 32;
  const int b_wave = (wave & 1) * 64;
  const int j_wave = (wave >> 1) * 16;
  const int fr = lane & 15, q = lane >> 4;
  const int lr = lane >> 2, jj = lane & 3;
  const int j0 = jb + j_wave + q*4;

  auto stage = [&](int k0, int bsel){
    unsigned char* Wa = lds[bsel];
    unsigned char* Wb = lds[bsel] + 8192;
    unsigned char* Ha = lds[bsel] + 16384;
    unsigned char* Hb = lds[bsel] + 24576;
#pragma unroll
    for(int p=0;p<2;p++){
      const int s = wave*2 + p;
      const int r = s*16 + lr;
      const int j = jj ^ ((r >> 1) & 3);
      const size_t ka = (size_t)k0 + j*16;
      const size_t wrow = (size_t)((r >> 5)*Hd + jb + (r & 31));
      gl_lds16(WA + wrow*Hd + ka, &Wa[s*1024]);
      gl_lds16(WB + wrow*Hd + ka, &Wb[s*1024]);
      gl_lds16(hA + (size_t)(mb + r)*Hd + ka, &Ha[s*1024]);
      gl_lds16(hB + (size_t)(mb + r)*Hd + ka, &Hb[s*1024]);
    }
  };

  stage(0, 0);

  // early c prefetch: 16 fp32 in VGPRs, latency hides under the K-loop
  float co[4][4];
#pragma unroll
  for(int bt=0;bt<4;bt++){
    const int b = mb + b_wave + bt*16 + fr;
    *(float4*)co[bt] = *(const float4*)&cin[(size_t)b*Hd + j0];
  }
  asm volatile("" ::: "memory");   // pin: do not sink the c loads into the epilogue

  int4v acc1[4][4], acc2[4][4];
#pragma unroll
  for(int g=0;g<4;g++)
#pragma unroll
    for(int bt=0;bt<4;bt++){
      acc1[g][bt] = (int4v){0,0,0,0};
      acc2[g][bt] = (int4v){0,0,0,0};
    }

  for(int kc=0; kc<8; kc++){
    __syncthreads();
    if(kc < 7) stage((kc+1)*64, (kc+1)&1);

    const unsigned char* Wa = lds[kc&1];
    const unsigned char* Wb = lds[kc&1] + 8192;
    const unsigned char* Ha = lds[kc&1] + 16384;
    const unsigned char* Hb = lds[kc&1] + 24576;

    int4v wa[4], wb[4], hf[4], lf[4];
#pragma unroll
    for(int g=0;g<4;g++){
      const int r = g*32 + j_wave + fr;
      const int off = r*64 + ((q ^ ((r >> 1) & 3)) << 4);
      wa[g] = *(const int4v*)&Wa[off];
      wb[g] = *(const int4v*)&Wb[off];
    }
#pragma unroll
    for(int bt=0;bt<4;bt++){
      const int r = b_wave + bt*16 + fr;
      const int off = r*64 + ((q ^ ((r >> 1) & 3)) << 4);
      hf[bt] = *(const int4v*)&Ha[off];
      lf[bt] = *(const int4v*)&Hb[off];
    }
#pragma unroll
    for(int g=0;g<4;g++)
#pragma unroll
      for(int bt=0;bt<4;bt++){
        acc1[g][bt] = __builtin_amdgcn_mfma_i32_16x16x64_i8(wa[g], hf[bt], acc1[g][bt], 0,0,0);
        acc2[g][bt] = __builtin_amdgcn_mfma_i32_16x16x64_i8(wa[g], lf[bt], acc2[g][bt], 0,0,0);
        acc2[g][bt] = __builtin_amdgcn_mfma_i32_16x16x64_i8(wb[g], hf[bt], acc2[g][bt], 0,0,0);
      }
  }

  float bsum[4][4];
#pragma unroll
  for(int g=0;g<4;g++){
    float4 a = *(const float4*)&bih[g*Hd + j0];
    float4 b = *(const float4*)&bhh[g*Hd + j0];
    bsum[g][0]=a.x+b.x; bsum[g][1]=a.y+b.y; bsum[g][2]=a.z+b.z; bsum[g][3]=a.w+b.w;
  }
#pragma unroll
  for(int bt=0;bt<4;bt++){
    const int b = mb + b_wave + bt*16 + fr;
    const size_t idx = (size_t)b*Hd + j0;
    float gv[4][4];
#pragma unroll
    for(int g=0;g<4;g++)
#pragma unroll
      for(int r=0;r<4;r++)
        gv[g][r] = fmaf(C1E, (float)acc1[g][bt][r],
                   fmaf(C2E, (float)acc2[g][bt][r], bsum[g][r]));
    float cn[4];
    signed char a4[4], b4[4];
#pragma unroll
    for(int r=0;r<4;r++){
      const float I = sigm_f(gv[0][r]);
      const float F = sigm_f(gv[1][r]);
      const float G = tanh_f(gv[2][r]);
      const float O = sigm_f(gv[3][r]);
      cn[r] = F*co[bt][r] + I*G;
      const float hn = O*tanh_f(cn[r]);
      i16split(hn, 32767.0f, a4[r], b4[r]);
    }
    *(float4*)&cout[idx] = *(float4*)cn;
    *(char4*)&hoA[idx] = *(char4*)a4;
    *(char4*)&hoB[idx] = *(char4*)b4;
  }
}

// ---------------------------------------------------------------------------
// Kernel A (steps >=1): i8 LSTM step with fused prev-step merge.
// R3 body + early c-tile register prefetch.
// ---------------------------------------------------------------------------
__global__ __launch_bounds__(256, 2) void k_lstm_i8(
    const signed char* __restrict__ hA, const signed char* __restrict__ hB,
    const float* __restrict__ cin,
    signed char* __restrict__ hoA, signed char* __restrict__ hoB,
    float* __restrict__ cout,
    const signed char* __restrict__ WA, const signed char* __restrict__ WB,
    const float* __restrict__ WihT, const float* __restrict__ bih,
    const float* __restrict__ bhh,
    const float* __restrict__ statM, const float* __restrict__ statS,
    const int* __restrict__ statI,
    float* __restrict__ msg, float* __restrict__ masks_out,
    float* __restrict__ lp_out, float* __restrict__ lpbuf,
    float* __restrict__ mbuf, int prev)
{
  __shared__ unsigned char lds[2][32768];
  __shared__ int gIs[128];
  const int tid = threadIdx.x;
  const int wave = tid >> 6, lane = tid & 63;
  const int tau = xcd_tau(128);
  const int mb = (tau >> 4) * 128;
  const int jb = (tau & 15) * 32;
  const int b_wave = (wave & 1) * 64;
  const int j_wave = (wave >> 1) * 16;
  const int fr = lane & 15, q = lane >> 4;
  const int lr = lane >> 2, jj = lane & 3;
  const int j0 = jb + j_wave + q*4;

  auto stage = [&](int k0, int bsel){
    unsigned char* Wa = lds[bsel];
    unsigned char* Wb = lds[bsel] + 8192;
    unsigned char* Ha = lds[bsel] + 16384;
    unsigned char* Hb = lds[bsel] + 24576;
#pragma unroll
    for(int p=0;p<2;p++){
      const int s = wave*2 + p;
      const int r = s*16 + lr;
      const int j = jj ^ ((r >> 1) & 3);
      const size_t ka = (size_t)k0 + j*16;
      const size_t wrow = (size_t)((r >> 5)*Hd + jb + (r & 31));
      gl_lds16(WA + wrow*Hd + ka, &Wa[s*1024]);
      gl_lds16(WB + wrow*Hd + ka, &Wb[s*1024]);
      gl_lds16(hA + (size_t)(mb + r)*Hd + ka, &Ha[s*1024]);
      gl_lds16(hB + (size_t)(mb + r)*Hd + ka, &Hb[s*1024]);
    }
  };

  stage(0, 0);   // async staging in flight during merge prologue

  // early c prefetch (cin==cout in-place, but this block only touches its own idx)
  float co[4][4];
#pragma unroll
  for(int bt=0;bt<4;bt++){
    const int b = mb + b_wave + bt*16 + fr;
    *(float4*)co[bt] = *(const float4*)&cin[(size_t)b*Hd + j0];
  }
  asm volatile("" ::: "memory");   // pin: keep the c loads here

  // ---- merge prologue: prev-step stats -> gi per row (+ scalar outputs)
  if(tid < 128){
    const int row = mb + tid;
    float gm = statM[row]; int gi = statI[row];
#pragma unroll
    for(int s=1;s<NSLAB;s++){
      const float m = statM[(size_t)s*Bsz + row];
      if(m > gm){ gm = m; gi = statI[(size_t)s*Bsz + row]; }
    }
    if(jb == 0){
      float tot = 0.0f;
#pragma unroll
      for(int s=0;s<NSLAB;s++)
        tot += statS[(size_t)s*Bsz + row] * __expf(statM[(size_t)s*Bsz + row] - gm);
      const float logp = -__logf(tot);
      const float mo  = (prev == 0) ? 1.0f : mbuf[row];
      const float lpo = (prev == 0) ? 0.0f : lpbuf[row];
      const float lpn = lpo + logp * mo;
      masks_out[(size_t)prev * Bsz + row] = mo;
      lp_out[row] = lpn;
      lpbuf[row]  = lpn;
      mbuf[row]   = mo * ((gi == Vd-1) ? 0.0f : 1.0f);
    }
    gIs[tid] = gi;
  }
  __syncthreads();

  // one-hot msg slice: this block writes cols [jb, jb+32) of prev-step msg
  {
    const int r  = tid >> 1;
    const int c0 = jb + (tid & 1) * 16;
    const int gi = gIs[r];
    float* mrow = msg + ((size_t)prev * Bsz + mb + r) * Vd;
#pragma unroll
    for(int i=0;i<4;i++){
      const int c = c0 + i*4;
      float4 v;
      v.x = (c   == gi) ? 1.0f : 0.0f;
      v.y = (c+1 == gi) ? 1.0f : 0.0f;
      v.z = (c+2 == gi) ? 1.0f : 0.0f;
      v.w = (c+3 == gi) ? 1.0f : 0.0f;
      *(float4*)&mrow[c] = v;
    }
  }

  int xid[4];
#pragma unroll
  for(int bt=0;bt<4;bt++)
    xid[bt] = gIs[b_wave + bt*16 + fr];

  int4v acc1[4][4], acc2[4][4];
#pragma unroll
  for(int g=0;g<4;g++)
#pragma unroll
    for(int bt=0;bt<4;bt++){
      acc1[g][bt] = (int4v){0,0,0,0};
      acc2[g][bt] = (int4v){0,0,0,0};
    }

  for(int kc=0; kc<8; kc++){
    __syncthreads();
    if(kc < 7) stage((kc+1)*64, (kc+1)&1);

    const unsigned char* Wa = lds[kc&1];
    const unsigned char* Wb = lds[kc&1] + 8192;
    const unsigned char* Ha = lds[kc&1] + 16384;
    const unsigned char* Hb = lds[kc&1] + 24576;

    int4v wa[4], wb[4], hf[4], lf[4];
#pragma unroll
    for(int g=0;g<4;g++){
      const int r = g*32 + j_wave + fr;
      const int off = r*64 + ((q ^ ((r >> 1) & 3)) << 4);
      wa[g] = *(const int4v*)&Wa[off];
      wb[g] = *(const int4v*)&Wb[off];
    }
#pragma unroll
    for(int bt=0;bt<4;bt++){
      const int r = b_wave + bt*16 + fr;
      const int off = r*64 + ((q ^ ((r >> 1) & 3)) << 4);
      hf[bt] = *(const int4v*)&Ha[off];
      lf[bt] = *(const int4v*)&Hb[off];
    }
#pragma unroll
    for(int g=0;g<4;g++)
#pragma unroll
      for(int bt=0;bt<4;bt++){
        acc1[g][bt] = __builtin_amdgcn_mfma_i32_16x16x64_i8(wa[g], hf[bt], acc1[g][bt], 0,0,0);
        acc2[g][bt] = __builtin_amdgcn_mfma_i32_16x16x64_i8(wa[g], lf[bt], acc2[g][bt], 0,0,0);
        acc2[g][bt] = __builtin_amdgcn_mfma_i32_16x16x64_i8(wb[g], hf[bt], acc2[g][bt], 0,0,0);
      }
  }

  float bsum[4][4];
#pragma unroll
  for(int g=0;g<4;g++){
    float4 a = *(const float4*)&bih[g*Hd + j0];
    float4 b = *(const float4*)&bhh[g*Hd + j0];
    bsum[g][0]=a.x+b.x; bsum[g][1]=a.y+b.y; bsum[g][2]=a.z+b.z; bsum[g][3]=a.w+b.w;
  }
#pragma unroll
  for(int bt=0;bt<4;bt++){
    const int b = mb + b_wave + bt*16 + fr;
    const size_t idx = (size_t)b*Hd + j0;
    float gv[4][4];
#pragma unroll
    for(int g=0;g<4;g++)
#pragma unroll
      for(int r=0;r<4;r++)
        gv[g][r] = fmaf(C1I, (float)acc1[g][bt][r],
                   fmaf(C2I, (float)acc2[g][bt][r], bsum[g][r]));
    {
      const float* grow = WihT + (size_t)xid[bt]*G4 + j0;
#pragma unroll
      for(int g=0;g<4;g++){
        float4 x = *(const float4*)&grow[g*Hd];
        gv[g][0]+=x.x; gv[g][1]+=x.y; gv[g][2]+=x.z; gv[g][3]+=x.w;
      }
    }
    float cn[4];
    signed char a4[4], b4[4];
#pragma unroll
    for(int r=0;r<4;r++){
      const float I = sigm_f(gv[0][r]);
      const float F = sigm_f(gv[1][r]);
      const float G = tanh_f(gv[2][r]);
      const float O = sigm_f(gv[3][r]);
      cn[r] = F*co[bt][r] + I*G;
      const float hn = O*tanh_f(cn[r]);
      i16split(hn, 32767.0f, a4[r], b4[r]);
    }
    *(float4*)&cout[idx] = *(float4*)cn;
    *(char4*)&hoA[idx] = *(char4*)a4;
    *(char4*)&hoB[idx] = *(char4*)b4;
  }
}

// ---------------------------------------------------------------------------
// Kernel B: logits STATS ONLY.  128x64 tile, grid (64,8), dbuf LDS.
// R3 body + bout/vv hoisted before the K-loop.
// ---------------------------------------------------------------------------
__global__ __launch_bounds__(256, 2) void k_logits_i8(
    const signed char* __restrict__ hA, const signed char* __restrict__ hB,
    const signed char* __restrict__ WoA, const signed char* __restrict__ WoB,
    const float* __restrict__ bout,
    float* __restrict__ statM, float* __restrict__ statS, int* __restrict__ statI)
{
  __shared__ unsigned char lds[2][24576];   // Ha 8K | Hb 8K | Wa 4K | Wb 4K
  const int tid = threadIdx.x;
  const int wave = tid >> 6, lane = tid & 63;
  const int tau = xcd_tau(64);
  const int mb = (tau >> 3) * 128;
  const int vb = (tau & 7) * 64;
  const int m_wave = (wave & 1) * 64;
  const int n_wave = (wave >> 1) * 32;
  const int fr = lane & 15, q = lane >> 4;
  const int lr = lane >> 2, jj = lane & 3;

  auto stage = [&](int k0, int bsel){
    unsigned char* Ha = lds[bsel];
    unsigned char* Hb = lds[bsel] + 8192;
    unsigned char* Wa = lds[bsel] + 16384;
    unsigned char* Wb = lds[bsel] + 20480;
#pragma unroll
    for(int p=0;p<2;p++){
      const int s = wave*2 + p;
      const int r = s*16 + lr;
      const int j = jj ^ ((r >> 1) & 3);
      const size_t ka = (size_t)k0 + j*16;
      gl_lds16(hA + (size_t)(mb + r)*Hd + ka, &Ha[s*1024]);
      gl_lds16(hB + (size_t)(mb + r)*Hd + ka, &Hb[s*1024]);
    }
    {
      const int r = wave*16 + lr;
      const int j = jj ^ ((r >> 1) & 3);
      const size_t ka = (size_t)k0 + j*16;
      gl_lds16(WoA + (size_t)(vb + r)*Hd + ka, &Wa[wave*1024]);
      gl_lds16(WoB + (size_t)(vb + r)*Hd + ka, &Wb[wave*1024]);
    }
  };

  stage(0, 0);

  // hoisted epilogue constants (latency hides under the K-loop)
  float bo[2];
  int vv[2];
#pragma unroll
  for(int nt=0;nt<2;nt++){
    vv[nt] = vb + n_wave + nt*16 + fr;
    bo[nt] = bout[vv[nt]];
  }
  asm volatile("" ::: "memory");

  int4v acc1[2][4], acc2[2][4];
#pragma unroll
  for(int nt=0;nt<2;nt++)
#pragma unroll
    for(int mt=0;mt<4;mt++){
      acc1[nt][mt] = (int4v){0,0,0,0};
      acc2[nt][mt] = (int4v){0,0,0,0};
    }

  for(int kc=0; kc<8; kc++){
    __syncthreads();
    if(kc < 7) stage((kc+1)*64, (kc+1)&1);

    const unsigned char* Ha = lds[kc&1];
    const unsigned char* Hb = lds[kc&1] + 8192;
    const unsigned char* Wa = lds[kc&1] + 16384;
    const unsigned char* Wb = lds[kc&1] + 20480;

    int4v ah[4], al[4], bh[2], bl[2];
#pragma unroll
    for(int mt=0;mt<4;mt++){
      const int r = m_wave + mt*16 + fr;
      const int off = r*64 + ((q ^ ((r >> 1) & 3)) << 4);
      ah[mt] = *(const int4v*)&Ha[off];
      al[mt] = *(const int4v*)&Hb[off];
    }
#pragma unroll
    for(int nt=0;nt<2;nt++){
      const int r = n_wave + nt*16 + fr;
      const int off = r*64 + ((q ^ ((r >> 1) & 3)) << 4);
      bh[nt] = *(const int4v*)&Wa[off];
      bl[nt] = *(const int4v*)&Wb[off];
    }
#pragma unroll
    for(int nt=0;nt<2;nt++)
#pragma unroll
      for(int mt=0;mt<4;mt++){
        acc1[nt][mt] = __builtin_amdgcn_mfma_i32_16x16x64_i8(ah[mt], bh[nt], acc1[nt][mt], 0,0,0);
        acc2[nt][mt] = __builtin_amdgcn_mfma_i32_16x16x64_i8(ah[mt], bl[nt], acc2[nt][mt], 0,0,0);
        acc2[nt][mt] = __builtin_amdgcn_mfma_i32_16x16x64_i8(al[mt], bh[nt], acc2[nt][mt], 0,0,0);
      }
  }

  const int slab = (vb >> 5) + (wave >> 1);
#pragma unroll
  for(int mt=0;mt<4;mt++){
#pragma unroll
    for(int reg=0;reg<4;reg++){
      float lg[2];
#pragma unroll
      for(int nt=0;nt<2;nt++)
        lg[nt] = fmaf(C1I, (float)acc1[nt][mt][reg],
                 fmaf(C2I, (float)acc2[nt][mt][reg], bo[nt]));
      float vmax = lg[0];
      int   imax = vv[0];
      if(lg[1] > vmax || (lg[1] == vmax && vv[1] < imax)){ vmax = lg[1]; imax = vv[1]; }
#pragma unroll
      for(int off=1; off<16; off<<=1){
        const float vo = __shfl_xor(vmax, off);
        const int   io = __shfl_xor(imax, off);
        if(vo > vmax || (vo == vmax && io < imax)){ vmax = vo; imax = io; }
      }
      float s = __expf(lg[0] - vmax) + __expf(lg[1] - vmax);
#pragma unroll
      for(int off=1; off<16; off<<=1) s += __shfl_xor(s, off);
      if(fr == 0){
        const int m = mb + m_wave + mt*16 + q*4 + reg;
        statM[(size_t)slab*Bsz + m] = vmax;
        statS[(size_t)slab*Bsz + m] = s;
        statI[(size_t)slab*Bsz + m] = imax;
      }
    }
  }
}

// ---------------------------------------------------------------------------
// Kernel C (final step only): merge 16 slabs, write msg/masks/lp.
// ---------------------------------------------------------------------------
__global__ __launch_bounds__(256) void k_merge(
    const float* __restrict__ statM, const float* __restrict__ statS,
    const int* __restrict__ statI,
    float* __restrict__ msg, float* __restrict__ masks_out,
    float* __restrict__ lp_out, float* __restrict__ lpbuf,
    float* __restrict__ mbuf, int step)
{
  __shared__ int gI[32];
  const int tid = threadIdx.x;
  const int mb = blockIdx.x * 32;

  if(tid < 32){
    const int row = mb + tid;
    float gm = statM[row]; int gi = statI[row];
#pragma unroll
    for(int s=1;s<NSLAB;s++){
      const float m = statM[(size_t)s*Bsz + row];
      if(m > gm){ gm = m; gi = statI[(size_t)s*Bsz + row]; }
    }
    float tot = 0.0f;
#pragma unroll
    for(int s=0;s<NSLAB;s++)
      tot += statS[(size_t)s*Bsz + row] * __expf(statM[(size_t)s*Bsz + row] - gm);
    const float logp = -__logf(tot);
    const float mo  = mbuf[row];
    const float lpn = lpbuf[row] + logp * mo;
    masks_out[(size_t)step * Bsz + row] = mo;
    lp_out[row] = lpn;
    gI[tid] = gi;
  }
  __syncthreads();

  const int r  = tid >> 3;
  const int c8 = tid & 7;
  const int gi = gI[r];
  float* mrow = msg + ((size_t)step * Bsz + mb + r) * Vd;
#pragma unroll
  for(int i=0;i<16;i++){
    const int c = (i*8 + c8) * 4;
    float4 v;
    v.x = (c   == gi) ? 1.0f : 0.0f;
    v.y = (c+1 == gi) ? 1.0f : 0.0f;
    v.z = (c+2 == gi) ? 1.0f : 0.0f;
    v.w = (c+3 == gi) ? 1.0f : 0.0f;
    *(float4*)&mrow[c] = v;
  }
}

// ---------------------------------------------------------------------------
extern "C" void kernel_launch(void* const* d_in, const int* in_sizes, int n_in,
                              void* d_out, int out_size, void* d_ws, size_t ws_size,
                              hipStream_t stream) {
  const float* enc_h = (const float*)d_in[0];
  const float* enc_c = (const float*)d_in[1];
  const float* Wih   = (const float*)d_in[2];
  const float* Whh   = (const float*)d_in[3];
  const float* bih   = (const float*)d_in[4];
  const float* bhh   = (const float*)d_in[5];
  const float* Wout  = (const float*)d_in[6];
  const float* bout  = (const float*)d_in[7];

  float* out_msg   = (float*)d_out;                       // [16][8192][512]
  float* out_masks = out_msg + (size_t)Ld * Bsz * Vd;     // [16][1][8192]
  float* out_lp    = out_masks + (size_t)Ld * Bsz;        // [8192]

  char* ws = (char*)d_ws;
  float* WihT  = (float*)ws;          ws += (size_t)Vd * G4 * 4;           // 4 MB
  signed char* WhhA = (signed char*)ws; ws += (size_t)G4 * Hd;             // 1 MB
  signed char* WhhB = (signed char*)ws; ws += (size_t)G4 * Hd;             // 1 MB
  signed char* WoA  = (signed char*)ws; ws += (size_t)Vd * Hd;             // 256 KB
  signed char* WoB  = (signed char*)ws; ws += (size_t)Vd * Hd;             // 256 KB
  signed char* encA = (signed char*)ws; ws += (size_t)Bsz * Hd;            // 4 MB
  signed char* encB = (signed char*)ws; ws += (size_t)Bsz * Hd;            // 4 MB
  signed char* ha0  = (signed char*)ws; ws += (size_t)Bsz * Hd;            // 4 MB
  signed char* hb0  = (signed char*)ws; ws += (size_t)Bsz * Hd;
  signed char* ha1  = (signed char*)ws; ws += (size_t)Bsz * Hd;
  signed char* hb1  = (signed char*)ws; ws += (size_t)Bsz * Hd;
  float* cbuf   = (float*)ws;  ws += (size_t)Bsz * Hd * 4;                 // 16 MB
  float* statM  = (float*)ws;  ws += (size_t)NSLAB * Bsz * 4;              // 512 KB
  float* statS  = (float*)ws;  ws += (size_t)NSLAB * Bsz * 4;
  int*   statI  = (int*)ws;    ws += (size_t)NSLAB * Bsz * 4;
  float* lpbuf  = (float*)ws;  ws += (size_t)Bsz * 4;
  float* mbuf   = (float*)ws;  ws += (size_t)Bsz * 4;

  k_prep<<<dim3(2048), dim3(256), 0, stream>>>(
      Wih, Whh, Wout, enc_h, WihT, WhhA, WhhB, WoA, WoB, encA, encB);

  for(int t=0; t<Ld; t++){
    signed char* haOut = (t & 1) ? ha1 : ha0;
    signed char* hbOut = (t & 1) ? hb1 : hb0;
    const signed char* haIn = (t & 1) ? ha0 : ha1;
    const signed char* hbIn = (t & 1) ? hb0 : hb1;

    if(t == 0){
      k_lstm_i8_first<<<dim3(Bsz/128, Hd/32), 256, 0, stream>>>(
          encA, encB, enc_c, haOut, hbOut, cbuf, WhhA, WhhB, bih, bhh);
    } else {
      k_lstm_i8<<<dim3(Bsz/128, Hd/32), 256, 0, stream>>>(
          haIn, hbIn, cbuf, haOut, hbOut, cbuf, WhhA, WhhB, WihT, bih, bhh,
          statM, statS, statI, out_msg, out_masks, out_lp, lpbuf, mbuf, t-1);
    }
    k_logits_i8<<<dim3(Bsz/128, Vd/64), 256, 0, stream>>>(
        haOut, hbOut, WoA, WoB, bout, statM, statS, statI);
  }
  k_merge<<<Bsz/32, 256, 0, stream>>>(statM, statS, statI,
                                      out_msg, out_masks, out_lp,
                                      lpbuf, mbuf, Ld-1);
}